// Round 12
// baseline (50.934 us; speedup 1.0000x reference)
//
#include <hip/hip_runtime.h>

namespace {

constexpr int S_LEN = 2048;
constexpr int H_N   = 8;
constexpr int D_DIM = 64;
constexpr int N_DIM = 32;
constexpr int TW    = 16;             // timesteps per chunk
constexpr int NKC   = S_LEN / TW;     // 128 chunks per (b,h)
constexpr float NLOG2E = -1.4426950408889634f;

// ws (all float):
//   sdtb: [kc][ch]        128*1024   (0.5 MB)  — sum of dt over chunk
//   bagg: [kc][ch][n]     128*1024*32 (16.8 MB) — chunk b-aggregate
//   pref: [kc][ch][n]     128*1024*32 (16.8 MB) — state entering chunk
// K1/K3: block = bh*64 + kcg (256 thr = 4 waves = 2 pairs); pair pp = w>>1 owns
// chunk kc = kcg*2+pp, dh = w&1. lane: dlow=lane&31, nh=lane>>5; d=dh*32+dlow;
// thread owns n in [nh*16, nh*16+16). ch = bh*64+d.
// No __syncthreads anywhere: B staged per-wave into private LDS, dt/u in regs,
// C read direct from global (VMEM pipe) to halve LDS-pipe ops.

__global__ __launch_bounds__(256, 4) void ssm_k1(
    const float* __restrict__ dtp, const float* __restrict__ up,
    const float* __restrict__ Ap,  const float* __restrict__ Bp,
    float* __restrict__ sdtb, float* __restrict__ bagg)
{
    __shared__ float lB[4][TW * 32];      // per-wave B slab (2 KB each)

    const int tid  = threadIdx.x;
    const int w    = tid >> 6;
    const int lane = tid & 63;
    const int pp   = w >> 1;
    const int dh   = w & 1;
    const int dlow = lane & 31;
    const int nh   = lane >> 5;
    const int bh   = blockIdx.x >> 6;
    const int kcg  = blockIdx.x & 63;
    const int kc   = kcg * 2 + pp;
    const int b = bh >> 3, hh = bh & 7;
    const int d  = dh * 32 + dlow;
    const int n0 = nh * 16;
    const int ch = bh * 64 + d;
    const int s0 = kc * TW;

    const int base_ud = b * (S_LEN * 512) + hh * 64 + d;
    const int bB      = b * (S_LEN * 256) + hh * 32 + s0 * 256;

    // ---- per-wave stage: B slab -> my LDS region ----
#pragma unroll
    for (int it = 0; it < 2; ++it) {
        const int idx = it * 64 + lane;           // 0..127 float4s
        const int row = idx >> 3, col = idx & 7;
        const float4 v = *(const float4*)(Bp + bB + row * 256 + col * 4);
        *(float4*)&lB[w][idx * 4] = v;
    }

    // ---- bulk prefetch dt/u into registers ----
    float dtv[TW], uv[TW];
#pragma unroll
    for (int t = 0; t < TW; ++t) {
        dtv[t] = dtp[base_ud + (s0 + t) * 512];
        uv[t]  = up [base_ud + (s0 + t) * 512];
    }

    float Aneg[16];
    {
        const float* Arow = Ap + (hh * D_DIM + d) * N_DIM + n0;
#pragma unroll
        for (int j = 0; j < 4; ++j) {
            float4 a4 = *(const float4*)(Arow + j * 4);
            Aneg[4*j+0] = NLOG2E * a4.x; Aneg[4*j+1] = NLOG2E * a4.y;
            Aneg[4*j+2] = NLOG2E * a4.z; Aneg[4*j+3] = NLOG2E * a4.w;
        }
    }

    float bA[16];
#pragma unroll
    for (int j = 0; j < 16; ++j) bA[j] = 0.0f;
    float sdt = 0.0f;

#pragma unroll 4
    for (int t = 0; t < TW; ++t) {
        const float kk = dtv[t] * uv[t];
        sdt += dtv[t];
#pragma unroll
        for (int j = 0; j < 4; ++j) {
            const float4 Bv = *(const float4*)&lB[w][t * 32 + n0 + j * 4];
#pragma unroll
            for (int q = 0; q < 4; ++q) {
                const int jn = j * 4 + q;
                const float bq = (q == 0) ? Bv.x : (q == 1) ? Bv.y : (q == 2) ? Bv.z : Bv.w;
                const float e = __builtin_amdgcn_exp2f(dtv[t] * Aneg[jn]);
                bA[jn] = fmaf(e, bA[jn], kk * bq);
            }
        }
    }

    if (nh == 0) sdtb[kc * 1024 + ch] = sdt;
    // vectorized aggregate store: [kc][ch][n0..n0+15] contiguous
    {
        float* dst = bagg + (size_t)kc * 32768 + ch * 32 + n0;
#pragma unroll
        for (int j = 0; j < 4; ++j)
            *(float4*)(dst + j * 4) = make_float4(bA[4*j+0], bA[4*j+1], bA[4*j+2], bA[4*j+3]);
    }
}

__global__ __launch_bounds__(256) void ssm_k2(
    const float* __restrict__ sdtb, const float* __restrict__ bagg,
    const float* __restrict__ Ap,   float* __restrict__ pref)
{
    const int T  = blockIdx.x * 256 + threadIdx.x;   // 32768 threads = (ch, n)
    const int ch = T >> 5;
    const int n  = T & 31;
    const int d  = ch & 63;
    const int hh = (ch >> 6) & 7;
    const float Aneg1 = NLOG2E * Ap[(hh * D_DIM + d) * N_DIM + n];

    const float* bp = bagg + (size_t)ch * 32 + n;
    float*       pq = pref + (size_t)ch * 32 + n;

    float p = 0.0f;
    for (int k = 0; k < NKC; k += 8) {
        float sd[8], bb[8];
#pragma unroll
        for (int i = 0; i < 8; ++i) {
            sd[i] = sdtb[(k + i) * 1024 + ch];
            bb[i] = bp[(size_t)(k + i) * 32768];
        }
#pragma unroll
        for (int i = 0; i < 8; ++i) {
            pq[(size_t)(k + i) * 32768] = p;
            const float a = __builtin_amdgcn_exp2f(Aneg1 * sd[i]);
            p = fmaf(a, p, bb[i]);
        }
    }
}

__global__ __launch_bounds__(256, 4) void ssm_k3(
    const float* __restrict__ dtp, const float* __restrict__ up,
    const float* __restrict__ Ap,  const float* __restrict__ Bp,
    const float* __restrict__ Cp,  const float* __restrict__ Dp,
    const float* __restrict__ pref, float* __restrict__ outp)
{
    __shared__ float lB[4][TW * 32];

    const int tid  = threadIdx.x;
    const int w    = tid >> 6;
    const int lane = tid & 63;
    const int pp   = w >> 1;
    const int dh   = w & 1;
    const int dlow = lane & 31;
    const int nh   = lane >> 5;
    const int bh   = blockIdx.x >> 6;
    const int kcg  = blockIdx.x & 63;
    const int kc   = kcg * 2 + pp;
    const int b = bh >> 3, hh = bh & 7;
    const int d  = dh * 32 + dlow;
    const int n0 = nh * 16;
    const int ch = bh * 64 + d;
    const int s0 = kc * TW;

    const int base_ud = b * (S_LEN * 512) + hh * 64 + d;
    const int bB      = b * (S_LEN * 256) + hh * 32 + s0 * 256;

    // ---- entering state: 4 contiguous float4 loads (coldest data first) ----
    float h[16];
    {
        const float* ps = pref + (size_t)kc * 32768 + ch * 32 + n0;
#pragma unroll
        for (int j = 0; j < 4; ++j) {
            float4 v = *(const float4*)(ps + j * 4);
            h[4*j+0] = v.x; h[4*j+1] = v.y; h[4*j+2] = v.z; h[4*j+3] = v.w;
        }
    }

    // ---- per-wave stage: B slab -> my LDS region ----
#pragma unroll
    for (int it = 0; it < 2; ++it) {
        const int idx = it * 64 + lane;
        const int row = idx >> 3, col = idx & 7;
        const float4 vb = *(const float4*)(Bp + bB + row * 256 + col * 4);
        *(float4*)&lB[w][idx * 4] = vb;
    }

    // ---- bulk prefetch dt/u ----
    float dtv[TW], uv[TW];
#pragma unroll
    for (int t = 0; t < TW; ++t) {
        dtv[t] = dtp[base_ud + (s0 + t) * 512];
        uv[t]  = up [base_ud + (s0 + t) * 512];
    }

    float Aneg[16];
    {
        const float* Arow = Ap + (hh * D_DIM + d) * N_DIM + n0;
#pragma unroll
        for (int j = 0; j < 4; ++j) {
            float4 a4 = *(const float4*)(Arow + j * 4);
            Aneg[4*j+0] = NLOG2E * a4.x; Aneg[4*j+1] = NLOG2E * a4.y;
            Aneg[4*j+2] = NLOG2E * a4.z; Aneg[4*j+3] = NLOG2E * a4.w;
        }
    }

    const float Dv = Dp[hh];

#pragma unroll 4
    for (int t = 0; t < TW; ++t) {
        const float kk = dtv[t] * uv[t];
        const float4* C4 = reinterpret_cast<const float4*>(Cp + bB + t * 256 + n0);
        float y0 = 0.0f, y1 = 0.0f, y2 = 0.0f, y3 = 0.0f;
#pragma unroll
        for (int j = 0; j < 4; ++j) {
            const float4 Bv = *(const float4*)&lB[w][t * 32 + n0 + j * 4];
            const float4 Cv = C4[j];      // direct global: VMEM pipe, L2/L3-hot broadcast
#pragma unroll
            for (int q = 0; q < 4; ++q) {
                const int jn = j * 4 + q;
                const float bq = (q == 0) ? Bv.x : (q == 1) ? Bv.y : (q == 2) ? Bv.z : Bv.w;
                const float cq = (q == 0) ? Cv.x : (q == 1) ? Cv.y : (q == 2) ? Cv.z : Cv.w;
                const float e = __builtin_amdgcn_exp2f(dtv[t] * Aneg[jn]);
                h[jn] = fmaf(e, h[jn], kk * bq);
                if (q == 0)      y0 = fmaf(h[jn], cq, y0);
                else if (q == 1) y1 = fmaf(h[jn], cq, y1);
                else if (q == 2) y2 = fmaf(h[jn], cq, y2);
                else             y3 = fmaf(h[jn], cq, y3);
            }
        }
        float y = (y0 + y1) + (y2 + y3);
        y += __shfl_xor(y, 32);
        if (nh == 0) outp[base_ud + (s0 + t) * 512] = fmaf(Dv, uv[t], y);
    }
}

} // namespace

extern "C" void kernel_launch(void* const* d_in, const int* in_sizes, int n_in,
                              void* d_out, int out_size, void* d_ws, size_t ws_size,
                              hipStream_t stream)
{
    const float* u  = (const float*)d_in[0];
    const float* dt = (const float*)d_in[1];
    const float* A  = (const float*)d_in[2];
    const float* B  = (const float*)d_in[3];
    const float* C  = (const float*)d_in[4];
    const float* D  = (const float*)d_in[5];
    float* out = (float*)d_out;

    float* sdtb = (float*)d_ws;                         // 0.5 MB
    float* bagg = sdtb + (size_t)NKC * 1024;            // 16.8 MB
    float* pref = bagg + (size_t)NKC * 32 * 1024;       // 16.8 MB

    ssm_k1<<<dim3(16 * 64), dim3(256), 0, stream>>>(dt, u, A, B, sdtb, bagg);
    ssm_k2<<<dim3(128),     dim3(256), 0, stream>>>(sdtb, bagg, A, pref);
    ssm_k3<<<dim3(16 * 64), dim3(256), 0, stream>>>(dt, u, A, B, C, D, pref, out);
}

// Round 13
// 47.285 us; speedup vs baseline: 1.0772x; 1.0772x over previous
//
#include <hip/hip_runtime.h>

namespace {

constexpr int S_LEN = 2048;
constexpr int H_N   = 8;
constexpr int D_DIM = 64;
constexpr int N_DIM = 32;
constexpr int TW    = 16;             // timesteps per chunk
constexpr int NKC   = S_LEN / TW;     // 128 chunks per (b,h)
constexpr int SEGL  = NKC / 4;        // 32 chunks per K2 segment
constexpr float NLOG2E = -1.4426950408889634f;

// ws (all float):
//   sdtb: [kc][ch]      128*1024    (0.5 MB)  — sum of dt over chunk
//   bagg: [kc][ch][n]   128*1024*32 (16.8 MB) — chunk b-aggregate (n contiguous)
//   pref: [kc][ch][n]   128*1024*32 (16.8 MB) — state entering chunk
// K1/K3: block = bh*64 + kcg (256 thr = 4 waves = 2 pairs); pair pp = w>>1 owns
// chunk kc = kcg*2+pp, dh = w&1. lane: dlow=lane&31, nh=lane>>5; d=dh*32+dlow;
// thread owns n in [nh*16, nh*16+16). ch = bh*64+d. No __syncthreads anywhere.
// K2: thread = (ch, n, seg) with seg in adjacent lanes; 4 segments of 32 chunks,
// register-cached scan + 4-lane shuffle composition (2048 waves = 8/CU).

__global__ __launch_bounds__(256, 4) void ssm_k1(
    const float* __restrict__ dtp, const float* __restrict__ up,
    const float* __restrict__ Ap,  const float* __restrict__ Bp,
    float* __restrict__ sdtb, float* __restrict__ bagg)
{
    __shared__ float lB[4][TW * 32];      // per-wave B slab (2 KB each)

    const int tid  = threadIdx.x;
    const int w    = tid >> 6;
    const int lane = tid & 63;
    const int pp   = w >> 1;
    const int dh   = w & 1;
    const int dlow = lane & 31;
    const int nh   = lane >> 5;
    const int bh   = blockIdx.x >> 6;
    const int kcg  = blockIdx.x & 63;
    const int kc   = kcg * 2 + pp;
    const int b = bh >> 3, hh = bh & 7;
    const int d  = dh * 32 + dlow;
    const int n0 = nh * 16;
    const int ch = bh * 64 + d;
    const int s0 = kc * TW;

    const int base_ud = b * (S_LEN * 512) + hh * 64 + d;
    const int bB      = b * (S_LEN * 256) + hh * 32 + s0 * 256;

    // ---- per-wave stage: B slab -> my LDS region ----
#pragma unroll
    for (int it = 0; it < 2; ++it) {
        const int idx = it * 64 + lane;           // 0..127 float4s
        const int row = idx >> 3, col = idx & 7;
        const float4 v = *(const float4*)(Bp + bB + row * 256 + col * 4);
        *(float4*)&lB[w][idx * 4] = v;
    }

    // ---- bulk prefetch dt/u into registers ----
    float dtv[TW], uv[TW];
#pragma unroll
    for (int t = 0; t < TW; ++t) {
        dtv[t] = dtp[base_ud + (s0 + t) * 512];
        uv[t]  = up [base_ud + (s0 + t) * 512];
    }

    float Aneg[16];
    {
        const float* Arow = Ap + (hh * D_DIM + d) * N_DIM + n0;
#pragma unroll
        for (int j = 0; j < 4; ++j) {
            float4 a4 = *(const float4*)(Arow + j * 4);
            Aneg[4*j+0] = NLOG2E * a4.x; Aneg[4*j+1] = NLOG2E * a4.y;
            Aneg[4*j+2] = NLOG2E * a4.z; Aneg[4*j+3] = NLOG2E * a4.w;
        }
    }

    float bA[16];
#pragma unroll
    for (int j = 0; j < 16; ++j) bA[j] = 0.0f;
    float sdt = 0.0f;

#pragma unroll 4
    for (int t = 0; t < TW; ++t) {
        const float kk = dtv[t] * uv[t];
        sdt += dtv[t];
#pragma unroll
        for (int j = 0; j < 4; ++j) {
            const float4 Bv = *(const float4*)&lB[w][t * 32 + n0 + j * 4];
#pragma unroll
            for (int q = 0; q < 4; ++q) {
                const int jn = j * 4 + q;
                const float bq = (q == 0) ? Bv.x : (q == 1) ? Bv.y : (q == 2) ? Bv.z : Bv.w;
                const float e = __builtin_amdgcn_exp2f(dtv[t] * Aneg[jn]);
                bA[jn] = fmaf(e, bA[jn], kk * bq);
            }
        }
    }

    if (nh == 0) sdtb[kc * 1024 + ch] = sdt;
    {
        float* dst = bagg + (size_t)kc * 32768 + ch * 32 + n0;
#pragma unroll
        for (int j = 0; j < 4; ++j)
            *(float4*)(dst + j * 4) = make_float4(bA[4*j+0], bA[4*j+1], bA[4*j+2], bA[4*j+3]);
    }
}

__global__ __launch_bounds__(256) void ssm_k2(
    const float* __restrict__ sdtb, const float* __restrict__ bagg,
    const float* __restrict__ Ap,   float* __restrict__ pref)
{
    const int T   = blockIdx.x * 256 + threadIdx.x;   // 131072 threads = (ch, n, seg)
    const int seg = T & 3;
    const int n   = (T >> 2) & 31;
    const int ch  = T >> 7;
    const int d   = ch & 63;
    const int hh  = (ch >> 6) & 7;
    const float Aneg1 = NLOG2E * Ap[(hh * D_DIM + d) * N_DIM + n];

    const int k0 = seg * SEGL;
    const size_t base = (size_t)ch * 32 + n;

    // ---- load segment data; convert sd -> a in place ----
    float bb[SEGL], av[SEGL];
#pragma unroll
    for (int i = 0; i < SEGL; ++i) {
        bb[i] = bagg[(size_t)(k0 + i) * 32768 + base];
        av[i] = sdtb[(k0 + i) * 1024 + ch];
    }
#pragma unroll
    for (int i = 0; i < SEGL; ++i)
        av[i] = __builtin_amdgcn_exp2f(Aneg1 * av[i]);

    // ---- segment transform (Aseg, bseg): p_out = Aseg*p_in + bseg ----
    float bseg = 0.0f, Aseg = 1.0f;
#pragma unroll
    for (int i = 0; i < SEGL; ++i) {
        bseg = fmaf(av[i], bseg, bb[i]);
        Aseg *= av[i];
    }

    // ---- 4-lane inclusive composition scan, then exclusive prefix ----
    {
        float Au = __shfl_up(Aseg, 1, 4), bu = __shfl_up(bseg, 1, 4);
        if (seg >= 1) { bseg = fmaf(Aseg, bu, bseg); Aseg *= Au; }
        Au = __shfl_up(Aseg, 2, 4); bu = __shfl_up(bseg, 2, 4);
        if (seg >= 2) { bseg = fmaf(Aseg, bu, bseg); Aseg *= Au; }
    }
    const float ebu = __shfl_up(bseg, 1, 4);
    float p = (seg == 0) ? 0.0f : ebu;     // state entering my segment

    // ---- rescan segment writing entering-state per chunk ----
#pragma unroll
    for (int i = 0; i < SEGL; ++i) {
        pref[(size_t)(k0 + i) * 32768 + base] = p;
        p = fmaf(av[i], p, bb[i]);
    }
}

__global__ __launch_bounds__(256, 4) void ssm_k3(
    const float* __restrict__ dtp, const float* __restrict__ up,
    const float* __restrict__ Ap,  const float* __restrict__ Bp,
    const float* __restrict__ Cp,  const float* __restrict__ Dp,
    const float* __restrict__ pref, float* __restrict__ outp)
{
    __shared__ float lB[4][TW * 32];
    __shared__ float lC[4][TW * 32];

    const int tid  = threadIdx.x;
    const int w    = tid >> 6;
    const int lane = tid & 63;
    const int pp   = w >> 1;
    const int dh   = w & 1;
    const int dlow = lane & 31;
    const int nh   = lane >> 5;
    const int bh   = blockIdx.x >> 6;
    const int kcg  = blockIdx.x & 63;
    const int kc   = kcg * 2 + pp;
    const int b = bh >> 3, hh = bh & 7;
    const int d  = dh * 32 + dlow;
    const int n0 = nh * 16;
    const int ch = bh * 64 + d;
    const int s0 = kc * TW;

    const int base_ud = b * (S_LEN * 512) + hh * 64 + d;
    const int bB      = b * (S_LEN * 256) + hh * 32 + s0 * 256;

    // ---- entering state: 4 contiguous float4 loads ----
    float h[16];
    {
        const float* ps = pref + (size_t)kc * 32768 + ch * 32 + n0;
#pragma unroll
        for (int j = 0; j < 4; ++j) {
            float4 v = *(const float4*)(ps + j * 4);
            h[4*j+0] = v.x; h[4*j+1] = v.y; h[4*j+2] = v.z; h[4*j+3] = v.w;
        }
    }

    // ---- per-wave stage: B and C slabs -> my LDS regions ----
#pragma unroll
    for (int it = 0; it < 2; ++it) {
        const int idx = it * 64 + lane;
        const int row = idx >> 3, col = idx & 7;
        const float4 vb = *(const float4*)(Bp + bB + row * 256 + col * 4);
        const float4 vc = *(const float4*)(Cp + bB + row * 256 + col * 4);
        *(float4*)&lB[w][idx * 4] = vb;
        *(float4*)&lC[w][idx * 4] = vc;
    }

    // ---- bulk prefetch dt/u ----
    float dtv[TW], uv[TW];
#pragma unroll
    for (int t = 0; t < TW; ++t) {
        dtv[t] = dtp[base_ud + (s0 + t) * 512];
        uv[t]  = up [base_ud + (s0 + t) * 512];
    }

    float Aneg[16];
    {
        const float* Arow = Ap + (hh * D_DIM + d) * N_DIM + n0;
#pragma unroll
        for (int j = 0; j < 4; ++j) {
            float4 a4 = *(const float4*)(Arow + j * 4);
            Aneg[4*j+0] = NLOG2E * a4.x; Aneg[4*j+1] = NLOG2E * a4.y;
            Aneg[4*j+2] = NLOG2E * a4.z; Aneg[4*j+3] = NLOG2E * a4.w;
        }
    }

    const float Dv = Dp[hh];

#pragma unroll 4
    for (int t = 0; t < TW; ++t) {
        const float kk = dtv[t] * uv[t];
        float y0 = 0.0f, y1 = 0.0f, y2 = 0.0f, y3 = 0.0f;
#pragma unroll
        for (int j = 0; j < 4; ++j) {
            const float4 Bv = *(const float4*)&lB[w][t * 32 + n0 + j * 4];
            const float4 Cv = *(const float4*)&lC[w][t * 32 + n0 + j * 4];
#pragma unroll
            for (int q = 0; q < 4; ++q) {
                const int jn = j * 4 + q;
                const float bq = (q == 0) ? Bv.x : (q == 1) ? Bv.y : (q == 2) ? Bv.z : Bv.w;
                const float cq = (q == 0) ? Cv.x : (q == 1) ? Cv.y : (q == 2) ? Cv.z : Cv.w;
                const float e = __builtin_amdgcn_exp2f(dtv[t] * Aneg[jn]);
                h[jn] = fmaf(e, h[jn], kk * bq);
                if (q == 0)      y0 = fmaf(h[jn], cq, y0);
                else if (q == 1) y1 = fmaf(h[jn], cq, y1);
                else if (q == 2) y2 = fmaf(h[jn], cq, y2);
                else             y3 = fmaf(h[jn], cq, y3);
            }
        }
        float y = (y0 + y1) + (y2 + y3);
        y += __shfl_xor(y, 32);
        if (nh == 0) outp[base_ud + (s0 + t) * 512] = fmaf(Dv, uv[t], y);
    }
}

} // namespace

extern "C" void kernel_launch(void* const* d_in, const int* in_sizes, int n_in,
                              void* d_out, int out_size, void* d_ws, size_t ws_size,
                              hipStream_t stream)
{
    const float* u  = (const float*)d_in[0];
    const float* dt = (const float*)d_in[1];
    const float* A  = (const float*)d_in[2];
    const float* B  = (const float*)d_in[3];
    const float* C  = (const float*)d_in[4];
    const float* D  = (const float*)d_in[5];
    float* out = (float*)d_out;

    float* sdtb = (float*)d_ws;                         // 0.5 MB
    float* bagg = sdtb + (size_t)NKC * 1024;            // 16.8 MB
    float* pref = bagg + (size_t)NKC * 32 * 1024;       // 16.8 MB

    ssm_k1<<<dim3(16 * 64), dim3(256), 0, stream>>>(dt, u, A, B, sdtb, bagg);
    ssm_k2<<<dim3(512),     dim3(256), 0, stream>>>(sdtb, bagg, A, pref);
    ssm_k3<<<dim3(16 * 64), dim3(256), 0, stream>>>(dt, u, A, B, C, D, pref, out);
}

// Round 14
// 43.369 us; speedup vs baseline: 1.1744x; 1.0903x over previous
//
#include <hip/hip_runtime.h>

namespace {

constexpr int S_LEN = 2048;
constexpr int H_N   = 8;
constexpr int D_DIM = 64;
constexpr int N_DIM = 32;
constexpr int TW    = 32;             // timesteps per chunk
constexpr int NKC   = S_LEN / TW;     // 64 chunks per (b,h)
constexpr int SEGL  = NKC / 4;        // 16 chunks per K2 segment
constexpr float NLOG2E = -1.4426950408889634f;

// ws (all float):
//   sdtb: [kc][ch]      64*1024    (0.25 MB) — sum of dt over chunk
//   bagg: [kc][ch][n]   64*1024*32 (8.4 MB)  — chunk b-aggregate (n contiguous)
//   pref: [kc][ch][n]   64*1024*32 (8.4 MB)  — state entering chunk
// K1/K3: block = bh*64 + kc (256 thr = 4 waves, ONE chunk per block).
//   wave w = d-quarter: d = w*16 + (lane&15); nq = lane>>4; n0 = nq*8.
//   Thread owns 8 n's. Barrier-free: per-wave private B/C LDS copies,
//   dt/u prefetched to regs in two 16-step sub-tiles.
// K2: thread = (ch, n, seg); 4 segments of 16 chunks, register scan +
//   4-lane shuffle composition (2048 waves).

__global__ __launch_bounds__(256, 4) void ssm_k1(
    const float* __restrict__ dtp, const float* __restrict__ up,
    const float* __restrict__ Ap,  const float* __restrict__ Bp,
    float* __restrict__ sdtb, float* __restrict__ bagg)
{
    __shared__ float lB[4][TW * 32];      // per-wave B slab (4 KB each)

    const int tid  = threadIdx.x;
    const int w    = tid >> 6;
    const int lane = tid & 63;
    const int dl   = lane & 15;
    const int nq   = lane >> 4;
    const int bh   = blockIdx.x >> 6;
    const int kc   = blockIdx.x & 63;
    const int b = bh >> 3, hh = bh & 7;
    const int d  = w * 16 + dl;
    const int n0 = nq * 8;
    const int ch = bh * 64 + d;
    const int s0 = kc * TW;

    const int base_ud = b * (S_LEN * 512) + hh * 64 + d;
    const int bB      = b * (S_LEN * 256) + hh * 32 + s0 * 256;

    // ---- per-wave stage: B slab (32 t x 32 n) -> my LDS copy ----
#pragma unroll
    for (int it = 0; it < 4; ++it) {
        const int idx = it * 64 + lane;           // 0..255 float4s
        const int row = idx >> 3, col = idx & 7;
        const float4 v = *(const float4*)(Bp + bB + row * 256 + col * 4);
        *(float4*)&lB[w][idx * 4] = v;
    }

    float Aneg[8];
    {
        const float* Arow = Ap + (hh * D_DIM + d) * N_DIM + n0;
#pragma unroll
        for (int j = 0; j < 2; ++j) {
            float4 a4 = *(const float4*)(Arow + j * 4);
            Aneg[4*j+0] = NLOG2E * a4.x; Aneg[4*j+1] = NLOG2E * a4.y;
            Aneg[4*j+2] = NLOG2E * a4.z; Aneg[4*j+3] = NLOG2E * a4.w;
        }
    }

    float bA[8];
#pragma unroll
    for (int j = 0; j < 8; ++j) bA[j] = 0.0f;
    float sdt = 0.0f;

#pragma unroll
    for (int st = 0; st < 2; ++st) {
        float dtv[16], uv[16];
#pragma unroll
        for (int t2 = 0; t2 < 16; ++t2) {
            const int s = s0 + st * 16 + t2;
            dtv[t2] = dtp[base_ud + s * 512];
            uv[t2]  = up [base_ud + s * 512];
        }
#pragma unroll 4
        for (int t2 = 0; t2 < 16; ++t2) {
            const int tt = st * 16 + t2;
            const float kk = dtv[t2] * uv[t2];
            sdt += dtv[t2];
#pragma unroll
            for (int j = 0; j < 2; ++j) {
                const float4 Bv = *(const float4*)&lB[w][tt * 32 + n0 + j * 4];
#pragma unroll
                for (int q = 0; q < 4; ++q) {
                    const int jn = j * 4 + q;
                    const float bq = (q == 0) ? Bv.x : (q == 1) ? Bv.y : (q == 2) ? Bv.z : Bv.w;
                    const float e = __builtin_amdgcn_exp2f(dtv[t2] * Aneg[jn]);
                    bA[jn] = fmaf(e, bA[jn], kk * bq);
                }
            }
        }
    }

    if (nq == 0) sdtb[kc * 1024 + ch] = sdt;
    {
        float* dst = bagg + (size_t)kc * 32768 + ch * 32 + n0;
        *(float4*)(dst + 0) = make_float4(bA[0], bA[1], bA[2], bA[3]);
        *(float4*)(dst + 4) = make_float4(bA[4], bA[5], bA[6], bA[7]);
    }
}

__global__ __launch_bounds__(256) void ssm_k2(
    const float* __restrict__ sdtb, const float* __restrict__ bagg,
    const float* __restrict__ Ap,   float* __restrict__ pref)
{
    const int T   = blockIdx.x * 256 + threadIdx.x;   // 131072 threads = (ch, n, seg)
    const int seg = T & 3;
    const int n   = (T >> 2) & 31;
    const int ch  = T >> 7;
    const int d   = ch & 63;
    const int hh  = (ch >> 6) & 7;
    const float Aneg1 = NLOG2E * Ap[(hh * D_DIM + d) * N_DIM + n];

    const int k0 = seg * SEGL;
    const size_t base = (size_t)ch * 32 + n;

    float bb[SEGL], av[SEGL];
#pragma unroll
    for (int i = 0; i < SEGL; ++i) {
        bb[i] = bagg[(size_t)(k0 + i) * 32768 + base];
        av[i] = sdtb[(k0 + i) * 1024 + ch];
    }
#pragma unroll
    for (int i = 0; i < SEGL; ++i)
        av[i] = __builtin_amdgcn_exp2f(Aneg1 * av[i]);

    float bseg = 0.0f, Aseg = 1.0f;
#pragma unroll
    for (int i = 0; i < SEGL; ++i) {
        bseg = fmaf(av[i], bseg, bb[i]);
        Aseg *= av[i];
    }

    {
        float Au = __shfl_up(Aseg, 1, 4), bu = __shfl_up(bseg, 1, 4);
        if (seg >= 1) { bseg = fmaf(Aseg, bu, bseg); Aseg *= Au; }
        Au = __shfl_up(Aseg, 2, 4); bu = __shfl_up(bseg, 2, 4);
        if (seg >= 2) { bseg = fmaf(Aseg, bu, bseg); Aseg *= Au; }
    }
    const float ebu = __shfl_up(bseg, 1, 4);
    float p = (seg == 0) ? 0.0f : ebu;

#pragma unroll
    for (int i = 0; i < SEGL; ++i) {
        pref[(size_t)(k0 + i) * 32768 + base] = p;
        p = fmaf(av[i], p, bb[i]);
    }
}

__global__ __launch_bounds__(256, 4) void ssm_k3(
    const float* __restrict__ dtp, const float* __restrict__ up,
    const float* __restrict__ Ap,  const float* __restrict__ Bp,
    const float* __restrict__ Cp,  const float* __restrict__ Dp,
    const float* __restrict__ pref, float* __restrict__ outp)
{
    __shared__ float lB[4][TW * 32];
    __shared__ float lC[4][TW * 32];

    const int tid  = threadIdx.x;
    const int w    = tid >> 6;
    const int lane = tid & 63;
    const int dl   = lane & 15;
    const int nq   = lane >> 4;
    const int bh   = blockIdx.x >> 6;
    const int kc   = blockIdx.x & 63;
    const int b = bh >> 3, hh = bh & 7;
    const int d  = w * 16 + dl;
    const int n0 = nq * 8;
    const int ch = bh * 64 + d;
    const int s0 = kc * TW;

    const int base_ud = b * (S_LEN * 512) + hh * 64 + d;
    const int bB      = b * (S_LEN * 256) + hh * 32 + s0 * 256;

    // ---- entering state: 2 contiguous float4 loads ----
    float h[8];
    {
        const float* ps = pref + (size_t)kc * 32768 + ch * 32 + n0;
        float4 v0 = *(const float4*)(ps + 0);
        float4 v1 = *(const float4*)(ps + 4);
        h[0] = v0.x; h[1] = v0.y; h[2] = v0.z; h[3] = v0.w;
        h[4] = v1.x; h[5] = v1.y; h[6] = v1.z; h[7] = v1.w;
    }

    // ---- per-wave stage: B and C slabs -> my LDS copies ----
#pragma unroll
    for (int it = 0; it < 4; ++it) {
        const int idx = it * 64 + lane;
        const int row = idx >> 3, col = idx & 7;
        const float4 vb = *(const float4*)(Bp + bB + row * 256 + col * 4);
        const float4 vc = *(const float4*)(Cp + bB + row * 256 + col * 4);
        *(float4*)&lB[w][idx * 4] = vb;
        *(float4*)&lC[w][idx * 4] = vc;
    }

    float Aneg[8];
    {
        const float* Arow = Ap + (hh * D_DIM + d) * N_DIM + n0;
#pragma unroll
        for (int j = 0; j < 2; ++j) {
            float4 a4 = *(const float4*)(Arow + j * 4);
            Aneg[4*j+0] = NLOG2E * a4.x; Aneg[4*j+1] = NLOG2E * a4.y;
            Aneg[4*j+2] = NLOG2E * a4.z; Aneg[4*j+3] = NLOG2E * a4.w;
        }
    }

    const float Dv = Dp[hh];

#pragma unroll
    for (int st = 0; st < 2; ++st) {
        float dtv[16], uv[16];
#pragma unroll
        for (int t2 = 0; t2 < 16; ++t2) {
            const int s = s0 + st * 16 + t2;
            dtv[t2] = dtp[base_ud + s * 512];
            uv[t2]  = up [base_ud + s * 512];
        }
#pragma unroll 4
        for (int t2 = 0; t2 < 16; ++t2) {
            const int tt = st * 16 + t2;
            const float kk = dtv[t2] * uv[t2];
            float y0 = 0.0f, y1 = 0.0f, y2 = 0.0f, y3 = 0.0f;
#pragma unroll
            for (int j = 0; j < 2; ++j) {
                const float4 Bv = *(const float4*)&lB[w][tt * 32 + n0 + j * 4];
                const float4 Cv = *(const float4*)&lC[w][tt * 32 + n0 + j * 4];
#pragma unroll
                for (int q = 0; q < 4; ++q) {
                    const int jn = j * 4 + q;
                    const float bq = (q == 0) ? Bv.x : (q == 1) ? Bv.y : (q == 2) ? Bv.z : Bv.w;
                    const float cq = (q == 0) ? Cv.x : (q == 1) ? Cv.y : (q == 2) ? Cv.z : Cv.w;
                    const float e = __builtin_amdgcn_exp2f(dtv[t2] * Aneg[jn]);
                    h[jn] = fmaf(e, h[jn], kk * bq);
                    if (q == 0)      y0 = fmaf(h[jn], cq, y0);
                    else if (q == 1) y1 = fmaf(h[jn], cq, y1);
                    else if (q == 2) y2 = fmaf(h[jn], cq, y2);
                    else             y3 = fmaf(h[jn], cq, y3);
                }
            }
            float y = (y0 + y1) + (y2 + y3);
            y += __shfl_xor(y, 16);
            y += __shfl_xor(y, 32);
            if (nq == 0) outp[base_ud + (s0 + tt) * 512] = fmaf(Dv, uv[t2], y);
        }
    }
}

} // namespace

extern "C" void kernel_launch(void* const* d_in, const int* in_sizes, int n_in,
                              void* d_out, int out_size, void* d_ws, size_t ws_size,
                              hipStream_t stream)
{
    const float* u  = (const float*)d_in[0];
    const float* dt = (const float*)d_in[1];
    const float* A  = (const float*)d_in[2];
    const float* B  = (const float*)d_in[3];
    const float* C  = (const float*)d_in[4];
    const float* D  = (const float*)d_in[5];
    float* out = (float*)d_out;

    float* sdtb = (float*)d_ws;                         // 0.25 MB
    float* bagg = sdtb + (size_t)NKC * 1024;            // 8.4 MB
    float* pref = bagg + (size_t)NKC * 32 * 1024;       // 8.4 MB

    ssm_k1<<<dim3(16 * NKC), dim3(256), 0, stream>>>(dt, u, A, B, sdtb, bagg);
    ssm_k2<<<dim3(512),      dim3(256), 0, stream>>>(sdtb, bagg, A, pref);
    ssm_k3<<<dim3(16 * NKC), dim3(256), 0, stream>>>(dt, u, A, B, C, D, pref, out);
}